// Round 1
// baseline (6602.996 us; speedup 1.0000x reference)
//
#include <hip/hip_runtime.h>
#include <math.h>

static inline int ceil_div(int a, int b) { return (a + b - 1) / b; }

// ---------------- CSR build ----------------
__global__ __launch_bounds__(256) void k_hist(const int* __restrict__ rows, int* __restrict__ cnt, int E) {
  int e = blockIdx.x * 256 + threadIdx.x;
  if (e < E) atomicAdd(&cnt[rows[e]], 1);
}

__global__ __launch_bounds__(1024) void k_scan(const int* __restrict__ cnt, int* __restrict__ row_ptr,
                                               int* __restrict__ cursor, int n) {
  __shared__ int sums[1024];
  int t = threadIdx.x;
  int CH = (n + 1023) >> 10;
  int base = t * CH;
  int s = 0;
  for (int i = 0; i < CH; i++) { int idx = base + i; if (idx < n) s += cnt[idx]; }
  sums[t] = s;
  __syncthreads();
  for (int off = 1; off < 1024; off <<= 1) {
    int v = (t >= off) ? sums[t - off] : 0;
    __syncthreads();
    sums[t] += v;
    __syncthreads();
  }
  int run = (t == 0) ? 0 : sums[t - 1];
  for (int i = 0; i < CH; i++) {
    int idx = base + i;
    if (idx < n) { row_ptr[idx] = run; cursor[idx] = run; run += cnt[idx]; }
  }
  if (t == 1023) row_ptr[n] = run;
}

__global__ __launch_bounds__(256) void k_scatter(const int* __restrict__ rows, const int* __restrict__ cols,
    const float* __restrict__ vals, int* __restrict__ cursor,
    int* __restrict__ csr_col, float* __restrict__ csr_val, int E) {
  int e = blockIdx.x * 256 + threadIdx.x;
  if (e < E) {
    int r = rows[e];
    int p = atomicAdd(&cursor[r], 1);
    csr_col[p] = cols[e];
    csr_val[p] = vals[e];
  }
}

// ---------------- fp32 tiled GEMM: C[N,M] = A[N,K] @ B[K,M], optional relu ----------------
__global__ __launch_bounds__(256) void k_gemm(const float* __restrict__ A, const float* __restrict__ B,
                                              float* __restrict__ C, int N, int K, int M, int relu) {
  __shared__ float As[16][132];
  __shared__ float Bs[16][132];
  const int tid = threadIdx.x;
  const int tx = tid & 15, ty = tid >> 4;
  const long rowBase = (long)blockIdx.x * 128;
  const long colBase = (long)blockIdx.y * 128;
  float acc[8][8];
#pragma unroll
  for (int i = 0; i < 8; i++)
#pragma unroll
    for (int j = 0; j < 8; j++) acc[i][j] = 0.f;

  const int ar = tid >> 1;          // 0..127
  const int akq = (tid & 1) * 8;    // 0 or 8
  const int bk = tid >> 4;          // 0..15
  const int bc = (tid & 15) * 8;    // 0..120

  for (int k0 = 0; k0 < K; k0 += 16) {
    // A tile 128x16
    {
      long grow = rowBase + ar;
      int kbase = k0 + akq;
      float av[8];
      if (grow < N && kbase + 7 < K) {
        const float* ap = A + grow * K + kbase;
        float4 v0 = *(const float4*)ap;
        float4 v1 = *(const float4*)(ap + 4);
        av[0] = v0.x; av[1] = v0.y; av[2] = v0.z; av[3] = v0.w;
        av[4] = v1.x; av[5] = v1.y; av[6] = v1.z; av[7] = v1.w;
      } else {
#pragma unroll
        for (int i = 0; i < 8; i++)
          av[i] = (grow < N && kbase + i < K) ? A[grow * K + kbase + i] : 0.f;
      }
#pragma unroll
      for (int i = 0; i < 8; i++) As[akq + i][ar] = av[i];
    }
    // B tile 16x128
    {
      int gk = k0 + bk;
      long gc = colBase + bc;
      float bv[8];
      if (gk < K && gc + 7 < M) {
        const float* bp = B + (long)gk * M + gc;
        float4 v0 = *(const float4*)bp;
        float4 v1 = *(const float4*)(bp + 4);
        bv[0] = v0.x; bv[1] = v0.y; bv[2] = v0.z; bv[3] = v0.w;
        bv[4] = v1.x; bv[5] = v1.y; bv[6] = v1.z; bv[7] = v1.w;
      } else {
#pragma unroll
        for (int i = 0; i < 8; i++)
          bv[i] = (gk < K && gc + i < M) ? B[(long)gk * M + gc + i] : 0.f;
      }
#pragma unroll
      for (int i = 0; i < 8; i++) Bs[bk][bc + i] = bv[i];
    }
    __syncthreads();
#pragma unroll
    for (int kk = 0; kk < 16; kk++) {
      float a[8], b[8];
      *(float4*)&a[0] = *(const float4*)&As[kk][ty * 4];
      *(float4*)&a[4] = *(const float4*)&As[kk][64 + ty * 4];
      *(float4*)&b[0] = *(const float4*)&Bs[kk][tx * 4];
      *(float4*)&b[4] = *(const float4*)&Bs[kk][64 + tx * 4];
#pragma unroll
      for (int i = 0; i < 8; i++)
#pragma unroll
        for (int j = 0; j < 8; j++) acc[i][j] += a[i] * b[j];
    }
    __syncthreads();
  }
#pragma unroll
  for (int i = 0; i < 8; i++) {
    long gr = rowBase + ((i < 4) ? (ty * 4 + i) : (64 + ty * 4 + i - 4));
    if (gr >= N) continue;
#pragma unroll
    for (int jb = 0; jb < 2; jb++) {
      long gc = colBase + jb * 64 + tx * 4;
      float v0 = acc[i][jb * 4 + 0], v1 = acc[i][jb * 4 + 1];
      float v2 = acc[i][jb * 4 + 2], v3 = acc[i][jb * 4 + 3];
      if (relu) { v0 = fmaxf(v0, 0.f); v1 = fmaxf(v1, 0.f); v2 = fmaxf(v2, 0.f); v3 = fmaxf(v3, 0.f); }
      if (gc + 3 < M) {
        float4 v = make_float4(v0, v1, v2, v3);
        *(float4*)&C[gr * M + gc] = v;
      } else {
        float vv[4] = {v0, v1, v2, v3};
        for (int q = 0; q < 4; q++)
          if (gc + q < M) C[gr * M + gc + q] = vv[q];
      }
    }
  }
}

// ---------------- SpMM, width d <= 512 (d % 4 == 0), one block per row ----------------
__global__ __launch_bounds__(128) void k_spmm_vec(const int* __restrict__ rp, const int* __restrict__ ci,
    const float* __restrict__ cv, const float* __restrict__ src, float* __restrict__ dst,
    int d, int relu) {
  int r = blockIdx.x;
  int c4 = threadIdx.x * 4;
  if (c4 >= d) return;
  int s = rp[r], e = rp[r + 1];
  float4 acc = make_float4(0.f, 0.f, 0.f, 0.f);
  for (int j = s; j < e; j++) {
    int c = ci[j];
    float v = cv[j];
    float4 xv = *(const float4*)(src + (long)c * d + c4);
    acc.x += v * xv.x; acc.y += v * xv.y; acc.z += v * xv.z; acc.w += v * xv.w;
  }
  if (relu) {
    acc.x = fmaxf(acc.x, 0.f); acc.y = fmaxf(acc.y, 0.f);
    acc.z = fmaxf(acc.z, 0.f); acc.w = fmaxf(acc.w, 0.f);
  }
  *(float4*)(dst + (long)r * d + c4) = acc;
}

// ---------------- SpMM width 10, one thread per row; optional relu / final softmax ----------------
__global__ __launch_bounds__(256) void k_spmm10(const int* __restrict__ rp, const int* __restrict__ ci,
    const float* __restrict__ cv, const float* __restrict__ src, float* __restrict__ dst,
    int n, int relu, int soft) {
  int r = blockIdx.x * 256 + threadIdx.x;
  if (r >= n) return;
  int s = rp[r], e = rp[r + 1];
  float acc[10] = {0.f, 0.f, 0.f, 0.f, 0.f, 0.f, 0.f, 0.f, 0.f, 0.f};
  for (int j = s; j < e; j++) {
    int c = ci[j];
    float v = cv[j];
    const float* p = src + (long)c * 10;
#pragma unroll
    for (int m = 0; m < 10; m++) acc[m] += v * p[m];
  }
  if (relu) {
#pragma unroll
    for (int m = 0; m < 10; m++) acc[m] = fmaxf(acc[m], 0.f);
  }
  if (soft) {
    float mx = acc[0];
#pragma unroll
    for (int m = 1; m < 10; m++) mx = fmaxf(mx, acc[m]);
    float ssum = 0.f;
#pragma unroll
    for (int m = 0; m < 10; m++) { acc[m] = expf(acc[m] - mx); ssum += acc[m]; }
    float inv = 1.f / ssum;
#pragma unroll
    for (int m = 0; m < 10; m++) acc[m] *= inv;
  }
  float* q = dst + (long)r * 10;
#pragma unroll
  for (int m = 0; m < 10; m++) q[m] = acc[m];
}

// ---------------- gate (2-way) + combine: c = m0*z + m1*h ----------------
__global__ __launch_bounds__(128) void k_gate_combine(const float* __restrict__ h, const float* __restrict__ zin,
    const float* __restrict__ Wm, const float* __restrict__ bm,
    float* __restrict__ cout, int d) {
  __shared__ float red[2][2];
  __shared__ float mbc[2];
  int r = blockIdx.x, tid = threadIdx.x;
  const float* hrow = h + (long)r * d;
  const float* zrow = zin + (long)r * d;
  float s0 = 0.f, s1 = 0.f;
  for (int i = tid * 4; i < d; i += 512) {
    float4 hv = *(const float4*)(hrow + i);
    float4 zv = *(const float4*)(zrow + i);
    float4 wa = *(const float4*)(Wm + i * 2);
    float4 wb = *(const float4*)(Wm + i * 2 + 4);
    s0 += hv.x * wa.x + hv.y * wa.z + hv.z * wb.x + hv.w * wb.z;
    s1 += hv.x * wa.y + hv.y * wa.w + hv.z * wb.y + hv.w * wb.w;
    float4 wc = *(const float4*)(Wm + (d + i) * 2);
    float4 wd = *(const float4*)(Wm + (d + i) * 2 + 4);
    s0 += zv.x * wc.x + zv.y * wc.z + zv.z * wd.x + zv.w * wd.z;
    s1 += zv.x * wc.y + zv.y * wc.w + zv.z * wd.y + zv.w * wd.w;
  }
  for (int off = 32; off > 0; off >>= 1) { s0 += __shfl_down(s0, off); s1 += __shfl_down(s1, off); }
  int wave = tid >> 6, lane = tid & 63;
  if (lane == 0) { red[wave][0] = s0; red[wave][1] = s1; }
  __syncthreads();
  if (tid == 0) {
    float l0 = red[0][0] + red[1][0] + bm[0];
    float l1 = red[0][1] + red[1][1] + bm[1];
    l0 = (l0 > 0.f) ? l0 : 0.01f * l0;
    l1 = (l1 > 0.f) ? l1 : 0.01f * l1;
    float mx = fmaxf(l0, l1);
    float e0 = expf(l0 - mx), e1 = expf(l1 - mx);
    float inv = 1.f / (e0 + e1);
    float m0 = e0 * inv, m1 = e1 * inv;
    float nrm = fmaxf(sqrtf(m0 * m0 + m1 * m1), 1e-12f);
    mbc[0] = m0 / nrm; mbc[1] = m1 / nrm;
  }
  __syncthreads();
  float m0 = mbc[0], m1 = mbc[1];
  for (int i = tid * 4; i < d; i += 512) {
    float4 hv = *(const float4*)(hrow + i);
    float4 zv = *(const float4*)(zrow + i);
    float4 o;
    o.x = m0 * zv.x + m1 * hv.x;
    o.y = m0 * zv.y + m1 * hv.y;
    o.z = m0 * zv.z + m1 * hv.z;
    o.w = m0 * zv.w + m1 * hv.w;
    *(float4*)(cout + (long)r * d + i) = o;
  }
}

// ---------------- layer-3 gate + fused (m0*z3 + m1*h3) @ W4 (2000x10), one block per row ----------------
__global__ __launch_bounds__(256) void k_gate4(const float* __restrict__ h3, const float* __restrict__ z3,
    const float* __restrict__ Wm3, const float* __restrict__ bm3,
    const float* __restrict__ W4, float* __restrict__ outv) {
  __shared__ float w4s[10000];   // 1000 rows x 10 per chunk
  __shared__ float red[4][10];
  __shared__ float mbc[2];
  int r = blockIdx.x, tid = threadIdx.x;
  const float* hrow = h3 + (long)r * 2000;
  const float* zrow = z3 + (long)r * 2000;
  float s0 = 0.f, s1 = 0.f;
  for (int i = tid * 4; i < 2000; i += 1024) {
    float4 hv = *(const float4*)(hrow + i);
    float4 zv = *(const float4*)(zrow + i);
    float4 wa = *(const float4*)(Wm3 + i * 2);
    float4 wb = *(const float4*)(Wm3 + i * 2 + 4);
    s0 += hv.x * wa.x + hv.y * wa.z + hv.z * wb.x + hv.w * wb.z;
    s1 += hv.x * wa.y + hv.y * wa.w + hv.z * wb.y + hv.w * wb.w;
    float4 wc = *(const float4*)(Wm3 + (2000 + i) * 2);
    float4 wd = *(const float4*)(Wm3 + (2000 + i) * 2 + 4);
    s0 += zv.x * wc.x + zv.y * wc.z + zv.z * wd.x + zv.w * wd.z;
    s1 += zv.x * wc.y + zv.y * wc.w + zv.z * wd.y + zv.w * wd.w;
  }
  for (int off = 32; off > 0; off >>= 1) { s0 += __shfl_down(s0, off); s1 += __shfl_down(s1, off); }
  int wave = tid >> 6, lane = tid & 63;
  if (lane == 0) { red[wave][0] = s0; red[wave][1] = s1; }
  __syncthreads();
  if (tid == 0) {
    float l0 = red[0][0] + red[1][0] + red[2][0] + red[3][0] + bm3[0];
    float l1 = red[0][1] + red[1][1] + red[2][1] + red[3][1] + bm3[1];
    l0 = (l0 > 0.f) ? l0 : 0.01f * l0;
    l1 = (l1 > 0.f) ? l1 : 0.01f * l1;
    float mx = fmaxf(l0, l1);
    float e0 = expf(l0 - mx), e1 = expf(l1 - mx);
    float inv = 1.f / (e0 + e1);
    float m0 = e0 * inv, m1 = e1 * inv;
    float nrm = fmaxf(sqrtf(m0 * m0 + m1 * m1), 1e-12f);
    mbc[0] = m0 / nrm; mbc[1] = m1 / nrm;
  }
  __syncthreads();
  float m0 = mbc[0], m1 = mbc[1];
  float acc[10] = {0.f, 0.f, 0.f, 0.f, 0.f, 0.f, 0.f, 0.f, 0.f, 0.f};
  for (int ch = 0; ch < 2; ch++) {
    __syncthreads();
    for (int i = tid; i < 10000; i += 256) w4s[i] = W4[ch * 10000 + i];
    __syncthreads();
    int base = ch * 1000;
    for (int i = tid * 4; i < 1000; i += 1024) {
      float4 hv = *(const float4*)(hrow + base + i);
      float4 zv = *(const float4*)(zrow + base + i);
      float c0 = m0 * zv.x + m1 * hv.x;
      float c1 = m0 * zv.y + m1 * hv.y;
      float c2 = m0 * zv.z + m1 * hv.z;
      float c3 = m0 * zv.w + m1 * hv.w;
      const float* w0 = &w4s[i * 10];
#pragma unroll
      for (int m = 0; m < 10; m++)
        acc[m] += c0 * w0[m] + c1 * w0[10 + m] + c2 * w0[20 + m] + c3 * w0[30 + m];
    }
  }
  for (int off = 32; off > 0; off >>= 1) {
#pragma unroll
    for (int m = 0; m < 10; m++) acc[m] += __shfl_down(acc[m], off);
  }
  if (lane == 0) {
#pragma unroll
    for (int m = 0; m < 10; m++) red[wave][m] = acc[m];
  }
  __syncthreads();
  if (tid < 10) outv[(long)r * 10 + tid] = red[0][tid] + red[1][tid] + red[2][tid] + red[3][tid];
}

// ---------------- final 5-way gate (u) + fused @ W5 (3020x10), one block per row ----------------
__global__ __launch_bounds__(256) void k_uy(const float* __restrict__ z1, const float* __restrict__ z2,
    const float* __restrict__ z3, const float* __restrict__ z4, const float* __restrict__ zin,
    const float* __restrict__ Wml, const float* __restrict__ bml,
    const float* __restrict__ W5, float* __restrict__ y) {
  __shared__ float cat[3020];
  __shared__ float red[4][10];
  __shared__ float ubc[5];
  int r = blockIdx.x, tid = threadIdx.x;
  for (int i = tid; i < 500; i += 256) {
    cat[i] = z1[(long)r * 500 + i];
    cat[500 + i] = z2[(long)r * 500 + i];
  }
  for (int i = tid; i < 2000; i += 256) cat[1000 + i] = z3[(long)r * 2000 + i];
  if (tid < 10) cat[3000 + tid] = z4[(long)r * 10 + tid];
  if (tid >= 16 && tid < 26) cat[3010 + tid - 16] = zin[(long)r * 10 + tid - 16];
  __syncthreads();
  float l[5] = {0.f, 0.f, 0.f, 0.f, 0.f};
  for (int i = tid; i < 3020; i += 256) {
    float c = cat[i];
    const float* w = Wml + (long)i * 5;
    l[0] += c * w[0]; l[1] += c * w[1]; l[2] += c * w[2]; l[3] += c * w[3]; l[4] += c * w[4];
  }
  for (int off = 32; off > 0; off >>= 1) {
#pragma unroll
    for (int m = 0; m < 5; m++) l[m] += __shfl_down(l[m], off);
  }
  int wave = tid >> 6, lane = tid & 63;
  if (lane == 0) {
#pragma unroll
    for (int m = 0; m < 5; m++) red[wave][m] = l[m];
  }
  __syncthreads();
  if (tid == 0) {
    float u[5];
    float mx = -1e30f;
#pragma unroll
    for (int m = 0; m < 5; m++) {
      float t = red[0][m] + red[1][m] + red[2][m] + red[3][m] + bml[m];
      t = (t > 0.f) ? t : 0.01f * t;
      u[m] = t;
      mx = fmaxf(mx, t);
    }
    float s = 0.f;
#pragma unroll
    for (int m = 0; m < 5; m++) { u[m] = expf(u[m] - mx); s += u[m]; }
    float inv = 1.f / s;
    float n2 = 0.f;
#pragma unroll
    for (int m = 0; m < 5; m++) { u[m] *= inv; n2 += u[m] * u[m]; }
    float nrm = fmaxf(sqrtf(n2), 1e-12f);
#pragma unroll
    for (int m = 0; m < 5; m++) ubc[m] = u[m] / nrm;
  }
  __syncthreads();
  for (int i = tid; i < 3020; i += 256) {
    int seg = (i < 500) ? 0 : (i < 1000) ? 1 : (i < 3000) ? 2 : (i < 3010) ? 3 : 4;
    cat[i] *= ubc[seg];
  }
  __syncthreads();
  float acc[10] = {0.f, 0.f, 0.f, 0.f, 0.f, 0.f, 0.f, 0.f, 0.f, 0.f};
  for (int i = tid; i < 3020; i += 256) {
    float c = cat[i];
    const float* w = W5 + (long)i * 10;
#pragma unroll
    for (int m = 0; m < 10; m++) acc[m] += c * w[m];
  }
  for (int off = 32; off > 0; off >>= 1) {
#pragma unroll
    for (int m = 0; m < 10; m++) acc[m] += __shfl_down(acc[m], off);
  }
  if (lane == 0) {
#pragma unroll
    for (int m = 0; m < 10; m++) red[wave][m] = acc[m];
  }
  __syncthreads();
  if (tid < 10) y[(long)r * 10 + tid] = red[0][tid] + red[1][tid] + red[2][tid] + red[3][tid];
}

extern "C" void kernel_launch(void* const* d_in, const int* in_sizes, int n_in,
                              void* d_out, int out_size, void* d_ws, size_t ws_size,
                              hipStream_t stream) {
  const float* x   = (const float*)d_in[0];
  const int* arow  = (const int*)d_in[1];
  const int* acol  = (const int*)d_in[2];
  const float* aval = (const float*)d_in[3];
  const float* h1  = (const float*)d_in[4];
  const float* h2  = (const float*)d_in[5];
  const float* h3  = (const float*)d_in[6];
  const float* zf  = (const float*)d_in[7];
  const float* W1  = (const float*)d_in[8];
  const float* W2  = (const float*)d_in[9];
  const float* W3  = (const float*)d_in[10];
  const float* W4  = (const float*)d_in[11];
  const float* W5  = (const float*)d_in[12];
  const float* Wm1 = (const float*)d_in[13];
  const float* bm1 = (const float*)d_in[14];
  const float* Wm2 = (const float*)d_in[15];
  const float* bm2 = (const float*)d_in[16];
  const float* Wm3 = (const float*)d_in[17];
  const float* bm3 = (const float*)d_in[18];
  const float* Wml = (const float*)d_in[19];
  const float* bml = (const float*)d_in[20];
  const int E = in_sizes[1];
  const int N = in_sizes[4] / 500;
  float* out = (float*)d_out;

  // workspace carve (total ~820 MB)
  char* p = (char*)d_ws;
  auto alloc = [&](size_t bytes) { char* q = p; p += (bytes + 255) & ~(size_t)255; return q; };
  float* z1      = (float*)alloc((size_t)N * 500 * 4);
  float* z2      = (float*)alloc((size_t)N * 500 * 4);
  float* z3      = (float*)alloc((size_t)N * 2000 * 4);
  float* tA      = (float*)alloc((size_t)N * 500 * 4);
  float* tB      = (float*)alloc((size_t)N * 500 * 4);
  float* xw4     = (float*)alloc((size_t)N * 10 * 4);
  float* z4      = (float*)alloc((size_t)N * 10 * 4);
  float* yb      = (float*)alloc((size_t)N * 10 * 4);
  int* cnt       = (int*)alloc((size_t)N * 4);
  int* row_ptr   = (int*)alloc((size_t)(N + 1) * 4);
  int* cursor    = (int*)alloc((size_t)N * 4);
  int* csr_col   = (int*)alloc((size_t)E * 4);
  float* csr_val = (float*)alloc((size_t)E * 4);

  // CSR build
  hipMemsetAsync(cnt, 0, (size_t)N * 4, stream);
  k_hist<<<ceil_div(E, 256), 256, 0, stream>>>(arow, cnt, E);
  k_scan<<<1, 1024, 0, stream>>>(cnt, row_ptr, cursor, N);
  k_scatter<<<ceil_div(E, 256), 256, 0, stream>>>(arow, acol, aval, cursor, csr_col, csr_val, E);

  dim3 g500(ceil_div(N, 128), ceil_div(500, 128));
  dim3 g2000(ceil_div(N, 128), ceil_div(2000, 128));

  // layer 1: z1 = relu(spmm(x@W1))
  k_gemm<<<g500, 256, 0, stream>>>(x, W1, tA, N, 2000, 500, 0);
  k_spmm_vec<<<N, 128, 0, stream>>>(row_ptr, csr_col, csr_val, tA, z1, 500, 1);
  // gate1 + combine -> tB
  k_gate_combine<<<N, 128, 0, stream>>>(h1, z1, Wm1, bm1, tB, 500);
  // layer 2: z2 = relu(spmm(c1@W2))
  k_gemm<<<g500, 256, 0, stream>>>(tB, W2, tA, N, 500, 500, 0);
  k_spmm_vec<<<N, 128, 0, stream>>>(row_ptr, csr_col, csr_val, tA, z2, 500, 1);
  // gate2 + combine -> tB
  k_gate_combine<<<N, 128, 0, stream>>>(h2, z2, Wm2, bm2, tB, 500);
  // layer 3 (reordered): s3 = spmm(c2), z3 = relu(s3@W3)
  k_spmm_vec<<<N, 128, 0, stream>>>(row_ptr, csr_col, csr_val, tB, tA, 500, 0);
  k_gemm<<<g2000, 256, 0, stream>>>(tA, W3, z3, N, 500, 2000, 1);
  // layer 4: gate3 fused with (m0*z3+m1*h3)@W4 -> xw4 ; z4 = relu(spmm(xw4))
  k_gate4<<<N, 256, 0, stream>>>(h3, z3, Wm3, bm3, W4, xw4);
  k_spmm10<<<ceil_div(N, 256), 256, 0, stream>>>(row_ptr, csr_col, csr_val, xw4, z4, N, 1, 0);
  // final: u gate + fused@W5 -> yb ; out = softmax(spmm(yb))
  k_uy<<<N, 256, 0, stream>>>(z1, z2, z3, z4, zf, Wml, bml, W5, yb);
  k_spmm10<<<ceil_div(N, 256), 256, 0, stream>>>(row_ptr, csr_col, csr_val, yb, out, N, 0, 1);
}